// Round 9
// baseline (3315.706 us; speedup 1.0000x reference)
//
#include <hip/hip_runtime.h>
#include <string.h>

// FPS: B=64 clouds, M=16384 pts, K=4096 selections. int32 output.
// One workgroup/cloud, 512 threads (8 waves), 32 pts/thread as 16 f16x2 pairs.
// Round-9 change (single, isolated): the per-iteration `outb[k]` GLOBAL store
// sat before __syncthreads, and hipcc drains vmcnt(0) before every s_barrier
// -> every iter serialized on a global-store L2 round-trip (~the unexplained
// ~700 cyc/iter). Winner indices now staged in LDS (u16 sout[4096], ds_write
// ~40cyc) and flushed to global once after the K-loop.

#define NCLOUDS 64
#define M 16384
#define KSEL 4096
#define NT 512
#define NPAIR 16
#define IDXMASK 0x3FFFu

typedef _Float16 h2 __attribute__((ext_vector_type(2)));
typedef unsigned short u16x2 __attribute__((ext_vector_type(2)));

static __device__ __forceinline__ unsigned int asu_h(h2 x) {
    return __builtin_bit_cast(unsigned int, x);
}
static __device__ __forceinline__ h2 ash(unsigned int x) {
    return __builtin_bit_cast(h2, x);
}
static __device__ __forceinline__ unsigned int asu_s(u16x2 x) {
    return __builtin_bit_cast(unsigned int, x);
}
static __device__ __forceinline__ u16x2 ass(unsigned int x) {
    return __builtin_bit_cast(u16x2, x);
}

static __device__ __forceinline__ unsigned int umax_(unsigned int a, unsigned int b) {
    return a > b ? a : b;
}
// Packed u16 min/max -> v_pk_min_u16 / v_pk_max_u16.
static __device__ __forceinline__ unsigned int pkmin_u(unsigned int a, unsigned int b) {
    return asu_s(__builtin_elementwise_min(ass(a), ass(b)));
}
static __device__ __forceinline__ unsigned int pkmax_u(unsigned int a, unsigned int b) {
    return asu_s(__builtin_elementwise_max(ass(a), ass(b)));
}

template <int CTRL>
static __device__ __forceinline__ unsigned int dpp_max(unsigned int v) {
    unsigned int s = (unsigned int)__builtin_amdgcn_update_dpp(
        0, (int)v, CTRL, 0xF, 0xF, false);
    return umax_(v, s);
}
// 64-lane max; valid in lane 63 (row_shr 1/2/4/8, bcast15, bcast31).
static __device__ __forceinline__ unsigned int wave_max63(unsigned int v) {
    v = dpp_max<0x111>(v);
    v = dpp_max<0x112>(v);
    v = dpp_max<0x114>(v);
    v = dpp_max<0x118>(v);
    v = dpp_max<0x142>(v);
    v = dpp_max<0x143>(v);
    return v;
}

static __device__ __forceinline__ unsigned int dup_lo(unsigned int u) {
    return (u & 0xffffu) | (u << 16);
}
static __device__ __forceinline__ unsigned int dup_hi(unsigned int u) {
    return (u >> 16) | (u & 0xffff0000u);
}

__global__ __launch_bounds__(NT) __attribute__((amdgpu_waves_per_eu(1, 2)))
void fps_kernel(const float* __restrict__ pos, int* __restrict__ out) {
    const int b = blockIdx.x, t = threadIdx.x, wid = t >> 6, lane = t & 63;

    __shared__ unsigned int   sxy[M];       // f16 x | f16 y<<16 per point: 64 KB
    __shared__ unsigned short szt[M];       // f16 z per point: 32 KB
    __shared__ unsigned short sout[KSEL];   // staged winner local indices: 8 KB
    __shared__ unsigned int   skey[2][8];   // double-buffered wave partials

    const float* __restrict__ cloud = pos + (size_t)b * (M * 3);
    int* __restrict__ outb = out + (size_t)b * KSEL;

    // Point (pair j, half h) lives at local index i = (2j+h)*NT + t.
    unsigned int hx[NPAIR], hy[NPAIR], hz[NPAIR], hd[NPAIR];

#pragma unroll
    for (int j = 0; j < NPAIR; ++j) {
        const int i0 = (2 * j) * NT + t, i1 = i0 + NT;
        const float x0 = cloud[i0 * 3 + 0], y0 = cloud[i0 * 3 + 1], z0 = cloud[i0 * 3 + 2];
        const float x1 = cloud[i1 * 3 + 0], y1 = cloud[i1 * 3 + 1], z1 = cloud[i1 * 3 + 2];
        h2 vx = {(_Float16)x0, (_Float16)x1};
        h2 vy = {(_Float16)y0, (_Float16)y1};
        h2 vz = {(_Float16)z0, (_Float16)z1};
        hx[j] = asu_h(vx); hy[j] = asu_h(vy); hz[j] = asu_h(vz);
        h2 p0 = {(_Float16)x0, (_Float16)y0};
        h2 p1 = {(_Float16)x1, (_Float16)y1};
        sxy[i0] = asu_h(p0);
        sxy[i1] = asu_h(p1);
        szt[i0] = (unsigned short)(hz[j] & 0xffffu);
        szt[i1] = (unsigned short)(hz[j] >> 16);
        asm volatile("" : "+v"(hx[j]), "+v"(hy[j]), "+v"(hz[j]));
    }

    // First sample: local index 0 (random_first=False). Staged in LDS.
    const _Float16 w0x = (_Float16)cloud[0];
    const _Float16 w0y = (_Float16)cloud[1];
    const _Float16 w0z = (_Float16)cloud[2];
    h2 wx2 = {w0x, w0x}, wy2 = {w0y, w0y}, wz2 = {w0z, w0z};
    if (t == 0) sout[0] = 0;

    // Init: hd[j] = (dist & 0xFFF0FFF0) | (j in low 4 bits of each half).
#pragma unroll
    for (int j = 0; j < NPAIR; ++j) {
        h2 dx = ash(hx[j]) - wx2;
        h2 dy = ash(hy[j]) - wy2;
        h2 dz = ash(hz[j]) - wz2;
        h2 s2 = dx * dx + dy * dy + dz * dz;
        hd[j] = (asu_h(s2) & 0xFFF0FFF0u) | ((unsigned int)j * 0x00010001u);
    }

    for (int k = 1; k < KSEL; ++k) {
        // ---- per-thread argmax fold: 15-op pkmax tree over hd ----
        unsigned int a8[8];
#pragma unroll
        for (int j = 0; j < 8; ++j) a8[j] = pkmax_u(hd[2 * j], hd[2 * j + 1]);
#pragma unroll
        for (int j = 0; j < 4; ++j) a8[j] = pkmax_u(a8[j], a8[j + 4]);
        a8[0] = pkmax_u(a8[0], a8[2]);
        a8[1] = pkmax_u(a8[1], a8[3]);
        const unsigned int mk = pkmax_u(a8[0], a8[1]);

        const unsigned int lo = mk & 0xffffu, hi = mk >> 16;
        const unsigned int best  = umax_(lo, hi);
        const unsigned int ibase = (hi > lo) ? (unsigned int)(t + NT) : (unsigned int)t;
        unsigned int key = (best << 10) | ibase;   // dist12|j4 in [25:10], i_local in [13:0]

        key = wave_max63(key);
        const int buf = k & 1;
        if (lane == 63) skey[buf][wid] = key;
        __syncthreads();   // single barrier per iteration; only LDS ops to drain

        unsigned int g = skey[buf][lane & 7];
        g = dpp_max<0x111>(g);
        g = dpp_max<0x112>(g);
        g = dpp_max<0x114>(g);
        const unsigned int gmax = (unsigned int)__builtin_amdgcn_readlane((int)g, 7);

        const int wi = (int)(gmax & IDXMASK);
        if (t == 0) sout[k] = (unsigned short)wi;   // LDS stage (no global store in loop)

        // Winner coords: LDS broadcast (f16), identical across all threads.
        const unsigned int wxy = sxy[wi];
        const unsigned int wzz = (unsigned int)szt[wi];
        wx2 = ash(dup_lo(wxy));
        wy2 = ash(dup_hi(wxy));
        wz2 = ash(dup_lo(wzz));

        // ---- fused packed min-update (8 ops/pair, slot stays embedded) ----
#pragma unroll
        for (int j = 0; j < NPAIR; ++j) {
            h2 dx = ash(hx[j]) - wx2;
            h2 dy = ash(hy[j]) - wy2;
            h2 dz = ash(hz[j]) - wz2;
            h2 s2 = dx * dx + dy * dy + dz * dz;
            const unsigned int kk =
                (asu_h(s2) & 0xFFF0FFF0u) | ((unsigned int)j * 0x00010001u);
            hd[j] = pkmin_u(hd[j], kk);
        }
    }

    // ---- epilogue: flush staged indices, coalesced ----
    __syncthreads();
#pragma unroll
    for (int r = 0; r < KSEL / NT; ++r) {
        const int i = r * NT + t;
        outb[i] = b * M + (int)sout[i];
    }
}

extern "C" void kernel_launch(void* const* d_in, const int* in_sizes, int n_in,
                              void* d_out, int out_size, void* d_ws, size_t ws_size,
                              hipStream_t stream) {
    const float* pos = (const float*)d_in[0];
    // d_in[1] (batch) is uniform B x M — unused.
    int* out = (int*)d_out;
    fps_kernel<<<dim3(NCLOUDS), dim3(NT), 0, stream>>>(pos, out);
}

// Round 11
// 3094.637 us; speedup vs baseline: 1.0714x; 1.0714x over previous
//
#include <hip/hip_runtime.h>
#include <string.h>

// FPS: B=64 clouds, M=16384 pts, K=4096 selections. int32 output.
// Round-10: 256 threads (4 waves), 64 pts/thread as 32 f16x2 pairs.
// Rationale: update issue per SIMD is invariant; shrink everything else.
// - fold fused into update loop (4 pkmax accumulators, 9 ops/pair)
// - 4 wave partials; final reduce = ds_read skey[lane&3] + 2 quad_perm DPP
//   max steps -> EVERY lane holds the global winner key (no readlane, no
//   SGPR hazard, no second dependent LDS read for the reduce)
// - hd embeds 5-bit pair id: dist11@[15:5] | j5@[4:0] per f16 half
// - block key = (best16<<9) | (h<<8) | t  => bits[13:0] = local index
// - waves_per_eu(1,1): VGPR cap 512, ~160 live regs stay in arch VGPRs

#define NCLOUDS 64
#define M 16384
#define KSEL 4096
#define NT 256
#define NPAIR 32
#define IDXMASK 0x3FFFu

typedef _Float16 h2 __attribute__((ext_vector_type(2)));
typedef unsigned short u16x2 __attribute__((ext_vector_type(2)));

static __device__ __forceinline__ unsigned int asu_h(h2 x) {
    return __builtin_bit_cast(unsigned int, x);
}
static __device__ __forceinline__ h2 ash(unsigned int x) {
    return __builtin_bit_cast(h2, x);
}
static __device__ __forceinline__ unsigned int asu_s(u16x2 x) {
    return __builtin_bit_cast(unsigned int, x);
}
static __device__ __forceinline__ u16x2 ass(unsigned int x) {
    return __builtin_bit_cast(u16x2, x);
}

static __device__ __forceinline__ unsigned int umax_(unsigned int a, unsigned int b) {
    return a > b ? a : b;
}
// Packed u16 min/max -> v_pk_min_u16 / v_pk_max_u16 (uint cmp == f16 cmp, d>=0).
static __device__ __forceinline__ unsigned int pkmin_u(unsigned int a, unsigned int b) {
    return asu_s(__builtin_elementwise_min(ass(a), ass(b)));
}
static __device__ __forceinline__ unsigned int pkmax_u(unsigned int a, unsigned int b) {
    return asu_s(__builtin_elementwise_max(ass(a), ass(b)));
}

template <int CTRL>
static __device__ __forceinline__ unsigned int dpp_max(unsigned int v) {
    unsigned int s = (unsigned int)__builtin_amdgcn_update_dpp(
        0, (int)v, CTRL, 0xF, 0xF, false);
    return umax_(v, s);
}
// 64-lane max; valid in lane 63 (row_shr 1/2/4/8, bcast15, bcast31).
static __device__ __forceinline__ unsigned int wave_max63(unsigned int v) {
    v = dpp_max<0x111>(v);
    v = dpp_max<0x112>(v);
    v = dpp_max<0x114>(v);
    v = dpp_max<0x118>(v);
    v = dpp_max<0x142>(v);
    v = dpp_max<0x143>(v);
    return v;
}

static __device__ __forceinline__ unsigned int dup_lo(unsigned int u) {
    return (u & 0xffffu) | (u << 16);
}
static __device__ __forceinline__ unsigned int dup_hi(unsigned int u) {
    return (u >> 16) | (u & 0xffff0000u);
}

__global__ __launch_bounds__(NT) __attribute__((amdgpu_waves_per_eu(1, 1)))
void fps_kernel(const float* __restrict__ pos, int* __restrict__ out) {
    const int b = blockIdx.x, t = threadIdx.x, wid = t >> 6, lane = t & 63;

    __shared__ unsigned int   sxy[M];      // f16 x | f16 y<<16 per point: 64 KB
    __shared__ unsigned short szt[M];      // f16 z per point: 32 KB
    __shared__ unsigned int   skey[2][4];  // double-buffered wave partials

    const float* __restrict__ cloud = pos + (size_t)b * (M * 3);
    int* __restrict__ outb = out + (size_t)b * KSEL;

    // Point (pair j, half h) lives at local index i = (2j+h)*NT + t.
    unsigned int hx[NPAIR], hy[NPAIR], hz[NPAIR], hd[NPAIR];

#pragma unroll
    for (int j = 0; j < NPAIR; ++j) {
        const int i0 = (2 * j) * NT + t, i1 = i0 + NT;
        const float x0 = cloud[i0 * 3 + 0], y0 = cloud[i0 * 3 + 1], z0 = cloud[i0 * 3 + 2];
        const float x1 = cloud[i1 * 3 + 0], y1 = cloud[i1 * 3 + 1], z1 = cloud[i1 * 3 + 2];
        h2 vx = {(_Float16)x0, (_Float16)x1};
        h2 vy = {(_Float16)y0, (_Float16)y1};
        h2 vz = {(_Float16)z0, (_Float16)z1};
        hx[j] = asu_h(vx); hy[j] = asu_h(vy); hz[j] = asu_h(vz);
        h2 p0 = {(_Float16)x0, (_Float16)y0};
        h2 p1 = {(_Float16)x1, (_Float16)y1};
        sxy[i0] = asu_h(p0);
        sxy[i1] = asu_h(p1);
        szt[i0] = (unsigned short)(hz[j] & 0xffffu);
        szt[i1] = (unsigned short)(hz[j] >> 16);
        asm volatile("" : "+v"(hx[j]), "+v"(hy[j]), "+v"(hz[j]));
    }

    // First sample: local index 0 (random_first=False).
    const _Float16 w0x = (_Float16)cloud[0];
    const _Float16 w0y = (_Float16)cloud[1];
    const _Float16 w0z = (_Float16)cloud[2];
    h2 wx2 = {w0x, w0x}, wy2 = {w0y, w0y}, wz2 = {w0z, w0z};
    if (t == 0) outb[0] = b * M;

    // Init: hd[j] = (dist & 0xFFE0FFE0) | j (5 bits per half).
    unsigned int acc0 = 0u, acc1 = 0u, acc2 = 0u, acc3 = 0u;
#pragma unroll
    for (int j = 0; j < NPAIR; ++j) {
        h2 dx = ash(hx[j]) - wx2;
        h2 dy = ash(hy[j]) - wy2;
        h2 dz = ash(hz[j]) - wz2;
        h2 s2 = dx * dx + dy * dy + dz * dz;
        hd[j] = (asu_h(s2) & 0xFFE0FFE0u) | ((unsigned int)j * 0x00010001u);
        if ((j & 3) == 0) acc0 = pkmax_u(acc0, hd[j]);
        else if ((j & 3) == 1) acc1 = pkmax_u(acc1, hd[j]);
        else if ((j & 3) == 2) acc2 = pkmax_u(acc2, hd[j]);
        else acc3 = pkmax_u(acc3, hd[j]);
    }

    for (int k = 1; k < KSEL; ++k) {
        // ---- per-thread fold (accumulators already hold running max) ----
        const unsigned int mk = pkmax_u(pkmax_u(acc0, acc1), pkmax_u(acc2, acc3));
        const unsigned int lo = mk & 0xffffu, hi = mk >> 16;
        const unsigned int best  = umax_(lo, hi);
        const unsigned int ibase = (hi > lo) ? (unsigned int)(t + NT) : (unsigned int)t;
        unsigned int key = (best << 9) | ibase;  // dist11|j5 @[24:9], h|t @[8:0]

        key = wave_max63(key);
        const int buf = k & 1;
        if (lane == 63) skey[buf][wid] = key;
        __syncthreads();   // single barrier per iteration

        // 4 partials -> global max in EVERY lane (2 quad_perm DPP steps).
        unsigned int g = skey[buf][lane & 3];
        g = dpp_max<0xB1>(g);   // quad_perm [1,0,3,2] : xor 1
        g = dpp_max<0x4E>(g);   // quad_perm [2,3,0,1] : xor 2
        const int wi = (int)(g & IDXMASK);

        if (t == 0) outb[k] = b * M + wi;

        // Winner coords: LDS broadcast (f16), identical across all threads.
        const unsigned int wxy = sxy[wi];
        const unsigned int wzz = (unsigned int)szt[wi];
        wx2 = ash(dup_lo(wxy));
        wy2 = ash(dup_hi(wxy));
        wz2 = ash(dup_lo(wzz));

        // ---- fused packed min-update + running argmax (9 ops/pair) ----
        acc0 = 0u; acc1 = 0u; acc2 = 0u; acc3 = 0u;
#pragma unroll
        for (int j = 0; j < NPAIR; ++j) {
            h2 dx = ash(hx[j]) - wx2;
            h2 dy = ash(hy[j]) - wy2;
            h2 dz = ash(hz[j]) - wz2;
            h2 s2 = dx * dx + dy * dy + dz * dz;
            const unsigned int kk =
                (asu_h(s2) & 0xFFE0FFE0u) | ((unsigned int)j * 0x00010001u);
            hd[j] = pkmin_u(hd[j], kk);
            if ((j & 3) == 0) acc0 = pkmax_u(acc0, hd[j]);
            else if ((j & 3) == 1) acc1 = pkmax_u(acc1, hd[j]);
            else if ((j & 3) == 2) acc2 = pkmax_u(acc2, hd[j]);
            else acc3 = pkmax_u(acc3, hd[j]);
        }
    }
}

extern "C" void kernel_launch(void* const* d_in, const int* in_sizes, int n_in,
                              void* d_out, int out_size, void* d_ws, size_t ws_size,
                              hipStream_t stream) {
    const float* pos = (const float*)d_in[0];
    // d_in[1] (batch) is uniform B x M — unused.
    int* out = (int*)d_out;
    fps_kernel<<<dim3(NCLOUDS), dim3(NT), 0, stream>>>(pos, out);
}